// Round 18
// baseline (7571.944 us; speedup 1.0000x reference)
//
#include <hip/hip_runtime.h>
#include <stdint.h>

// BiLSTM on MI355X — persistent recurrent kernel, R18 (= R17 with the
// inline-asm constraint fixed: ext_vector payload for global_store_dwordx4).
// Three measured-term fixes vs R13/R16 (6.55 ms k_rec):
// (1) Consumer h loads = plain global_load_dwordx4 sc0 sc1 (MALL-direct,
//     coalesced) — DELETES the per-step L1/L2 acquire-invalidate storm.
// (2) Producer h publish staged through LDS, then 128x16B sc0sc1 stores
//     (4x fewer MALL write transactions in the pre-tag vmcnt drain).
// (3) sG row stride 128 -> 129 floats (epilogue reads were 4-way bank
//     conflicted: SQ_LDS_BANK_CONFLICT 2.9e7/dispatch ~ 900cy/WG-step).
// Protocol otherwise R13: wave0 polls 16 relaxed 64B-strided tags, B1
// release, B2/B3 around sG accumulate, B4 before publish, tag after drain.
// W_h panel in LDS (XOR-swizzled). Backward dir: hk.ResetCore — state
// zeroed before flipped step t when t <= L - len[b]. OUTPUT IS FP32.

typedef __attribute__((ext_vector_type(8))) short  short8;
typedef __attribute__((ext_vector_type(4))) float  floatx4;
typedef __attribute__((ext_vector_type(4))) unsigned int uintx4;

#define LSEQ 1024
#define NB   32
#define DD   512
#define HH   512
#define NG   2048
#define SGS  129   // sG row stride in floats (bank-conflict pad)

// ---- workspace layout (bytes) ----
#define WX_OFF  0ul                           // bf16 [dir][n][k]   4 MiB
#define WH_OFF  (4ul<<20)                     // bf16 [dir][n][k]   4 MiB
#define X_OFF   (8ul<<20)                     // bf16 [t][b][d]    32 MiB (unflipped)
#define H_OFF   (40ul<<20)                    // bf16 h ping-pong [dir][par][b][h] 256 KiB
#define RST_OFF ((40ul<<20)+(384ul<<10))      // u32 [1024]
#define TAG_OFF ((40ul<<20)+(388ul<<10))      // int [2][16][16] tags, 64B-strided slots
#define Z_OFF   (41ul<<20)                    // [dir][step][b][n]
#define ZF_BYTES (2ul*LSEQ*NB*NG*4)           // 512 MiB
#define ZB_BYTES (2ul*LSEQ*NB*NG*2)           // 256 MiB
#define WS_NEED_F32 (Z_OFF + ZF_BYTES)
#define WS_NEED_B16 (Z_OFF + ZB_BYTES)

__device__ inline uint16_t f2bf(float f) {
  uint32_t u = __float_as_uint(f);
  u += 0x7fff + ((u >> 16) & 1);              // RNE
  return (uint16_t)(u >> 16);
}
__device__ inline float fsigm(float x) { return 1.0f / (1.0f + __expf(-x)); }
__device__ inline float ftanh(float x) { return 1.0f - 2.0f / (__expf(2.0f * x) + 1.0f); }

template <typename ZT> __device__ inline void zstore(ZT* p, float v);
template <> __device__ inline void zstore<float>(float* p, float v) { *p = v; }
template <> __device__ inline void zstore<uint16_t>(uint16_t* p, float v) { *p = f2bf(v); }

template <typename ZT> __device__ inline float2 zld2(const ZT* p);
template <> __device__ inline float2 zld2<float>(const float* p) { return *(const float2*)p; }
template <> __device__ inline float2 zld2<uint16_t>(const uint16_t* p) {
  uint32_t u = *(const uint32_t*)p;
  float2 r;
  r.x = __uint_as_float((u & 0xffffu) << 16);
  r.y = __uint_as_float(u & 0xffff0000u);
  return r;
}

// MALL-direct coalesced 16B load (bypass L1+L2). Caller waits vmcnt.
__device__ inline short8 mload16(const uint16_t* p) {
  short8 v;
  asm volatile("global_load_dwordx4 %0, %1, off sc0 sc1"
               : "=v"(v) : "v"(p));
  return v;
}
// MALL-direct 16B write-through store (ext_vector payload).
__device__ inline void mstore16(uint16_t* p, uintx4 v) {
  asm volatile("global_store_dwordx4 %0, %1, off sc0 sc1"
               :: "v"(p), "v"(v) : "memory");
}

// ---------------- K0: init H, tags, reset masks ----------------
__global__ void k_init(const int* __restrict__ len, uint32_t* __restrict__ rst,
                       int* __restrict__ tags, uint16_t* __restrict__ H)
{
  int tid = blockIdx.x * blockDim.x + threadIdx.x;
  int stride = gridDim.x * blockDim.x;
  for (int i = tid; i < 512; i += stride) tags[i] = 0;
  for (int i = tid; i < 2 * 2 * NB * HH; i += stride) H[i] = 0;
  for (int t = tid; t < LSEQ; t += stride) {
    uint32_t m = 0;
    for (int b = 0; b < NB; ++b)
      m |= ((uint32_t)(t <= LSEQ - len[b])) << b;   // reset BEFORE flipped step t
    rst[t] = m;
  }
}

// ---------------- K1: W fp32 -> bf16, transpose to [n][k] ----------------
__global__ void k_wcast(const float* __restrict__ Wf, const float* __restrict__ Wb,
                        uint16_t* __restrict__ WX, uint16_t* __restrict__ WH)
{
  int tid = blockIdx.x * blockDim.x + threadIdx.x;   // [0, 2^20)
  if (tid >= 2 * 1024 * 512) return;
  int dir = tid >> 19;
  int r = tid & ((1 << 19) - 1);
  int k = r >> 9;                  // row of W (0..1023)
  int n4 = (r & 511) * 4;          // gate-col group
  const float* W = dir ? Wb : Wf;
  const float4 v = *(const float4*)(W + (size_t)k * NG + n4);
  uint16_t* dst;
  int kk;
  if (k < DD) { dst = WX + (size_t)dir * NG * DD; kk = k; }
  else        { dst = WH + (size_t)dir * NG * HH; kk = k - DD; }
  dst[(size_t)(n4 + 0) * 512 + kk] = f2bf(v.x);
  dst[(size_t)(n4 + 1) * 512 + kk] = f2bf(v.y);
  dst[(size_t)(n4 + 2) * 512 + kk] = f2bf(v.z);
  dst[(size_t)(n4 + 3) * 512 + kk] = f2bf(v.w);
}

// ---------------- K2: x fp32 -> bf16 time-major [t][b][d] ----------------
__global__ void k_xcast(const float* __restrict__ x, uint16_t* __restrict__ X)
{
  int i4 = blockIdx.x * blockDim.x + threadIdx.x;    // [0, 2^22)
  if (i4 >= (NB * LSEQ * DD) / 4) return;
  int d4 = (i4 & 127) * 4;
  int t  = (i4 >> 7) & 1023;
  int b  = i4 >> 17;
  const float4 v = *(const float4*)(x + (size_t)i4 * 4);
  uint32_t lo = (uint32_t)f2bf(v.x) | ((uint32_t)f2bf(v.y) << 16);
  uint32_t hi = (uint32_t)f2bf(v.z) | ((uint32_t)f2bf(v.w) << 16);
  uint2 u; u.x = lo; u.y = hi;
  *(uint2*)(X + ((size_t)t * NB + b) * DD + d4) = u;
}

// ---------------- K3: Z[dir][step][b][:] = x[dir-step] @ Wx + b ----------------
template <typename ZT>
__global__ __launch_bounds__(256) void k_zgemm(
    const uint16_t* __restrict__ X, const uint16_t* __restrict__ WX,
    const float* __restrict__ bf_, const float* __restrict__ bb_,
    ZT* __restrict__ Z)
{
  __shared__ uint16_t sA[128 * 32];
  __shared__ uint16_t sB[128 * 32];

  const int bid = blockIdx.x;
  const int dir = bid >> 12;
  const int rem = bid & 4095;
  const int mtile = rem >> 4;     // 0..255 (dir-local M rows = step*32+b)
  const int ntile = rem & 15;     // 0..15
  const int tid = threadIdx.x;
  const int lane = tid & 63;
  const int w = tid >> 6;
  const int wm = (w >> 1) * 64;
  const int wn = (w & 1) * 64;

  const uint16_t* B = WX + (size_t)dir * NG * 512 + (size_t)(ntile * 128) * 512;
  const float* bias = (dir ? bb_ : bf_) + ntile * 128;

  uint4 ra[2], rb[2];
  auto load_tile = [&](int kk) {
#pragma unroll
    for (int j = 0; j < 2; ++j) {
      int c = tid + 256 * j;
      int row = c >> 2, ko = (c & 3) * 8;
      int grow = mtile * 128 + row;             // dir-local row
      int step = grow >> 5, bb = grow & 31;
      int srow = dir ? ((1023 - step) * 32 + bb) : grow;  // flip time for bwd
      ra[j] = *(const uint4*)(X + (size_t)srow * 512 + kk * 32 + ko);
      rb[j] = *(const uint4*)(B + (size_t)row * 512 + kk * 32 + ko);
    }
  };
  auto write_tile = [&]() {
#pragma unroll
    for (int j = 0; j < 2; ++j) {
      int c = tid + 256 * j;
      int row = c >> 2, ko = (c & 3) * 8;
      *(uint4*)(sA + row * 32 + ko) = ra[j];
      *(uint4*)(sB + row * 32 + ko) = rb[j];
    }
  };

  floatx4 acc[4][4];
#pragma unroll
  for (int m = 0; m < 4; ++m)
#pragma unroll
    for (int n = 0; n < 4; ++n)
#pragma unroll
      for (int r = 0; r < 4; ++r) acc[m][n][r] = 0.f;

  load_tile(0);
  for (int kk = 0; kk < 16; ++kk) {
    __syncthreads();
    write_tile();
    __syncthreads();
    if (kk < 15) load_tile(kk + 1);
    short8 af[4], bb8[4];
#pragma unroll
    for (int m = 0; m < 4; ++m)
      af[m] = *(const short8*)(sA + (wm + m * 16 + (lane & 15)) * 32 + (lane >> 4) * 8);
#pragma unroll
    for (int n = 0; n < 4; ++n)
      bb8[n] = *(const short8*)(sB + (wn + n * 16 + (lane & 15)) * 32 + (lane >> 4) * 8);
#pragma unroll
    for (int m = 0; m < 4; ++m)
#pragma unroll
      for (int n = 0; n < 4; ++n)
        acc[m][n] = __builtin_amdgcn_mfma_f32_16x16x32_bf16(af[m], bb8[n], acc[m][n], 0, 0, 0);
  }

  ZT* Zo = Z + ((size_t)dir * 32768 + (size_t)mtile * 128) * 2048 + ntile * 128;
#pragma unroll
  for (int n = 0; n < 4; ++n) {
    int col = wn + n * 16 + (lane & 15);
    float bv = bias[col];
#pragma unroll
    for (int m = 0; m < 4; ++m) {
      int row0 = wm + m * 16 + (lane >> 4) * 4;
#pragma unroll
      for (int r = 0; r < 4; ++r)
        zstore<ZT>(Zo + (size_t)(row0 + r) * 2048 + col, acc[m][n][r] + bv);
    }
  }
}

// ---------------- K4: persistent recurrent kernel ----------------
// grid = 32 WGs x 512 threads, 1 WG/CU. WG = (dir, panel p) owns h-cols
// [32p,32p+32) of all 4 gates. 8 waves = gate(4) x khalf(2). W_h in LDS.
template <typename ZT>
__global__ __launch_bounds__(512, 2) void k_rec(
    const uint16_t* __restrict__ WH, const ZT* __restrict__ Z,
    const uint32_t* __restrict__ rst, uint16_t* __restrict__ hbuf,
    int* __restrict__ tags, float* __restrict__ out)
{
  __shared__ uint16_t sW[128 * 512];   // 128 KB W_h panel, XOR-swizzled
  __shared__ float sG[NB * SGS];       // gate sums, padded stride (16.1 KB)
  __shared__ uint16_t sH[NB * 32];     // 2 KB h-publish staging

  const int tid = threadIdx.x;
  const int lane = tid & 63;
  const int wid = tid >> 6;
  const int gate = wid & 3;
  const int khalf = wid >> 2;
  const int dir = blockIdx.x >> 4;
  const int p = blockIdx.x & 15;

  const int r0 = lane & 15;               // A row / B col within 16-tile
  const int k8 = (lane >> 4) * 8;         // k offset within 32-slice

  // ---- stage W_h panel into LDS once (XOR-swizzled rows) ----
  {
    const uint16_t* Wg = WH + (size_t)dir * NG * HH;
    for (int i = tid; i < 8192; i += 512) {
      int lrow = i >> 6;                  // 0..127 panel row
      int k16  = i & 63;                  // 16B chunk within row
      int n = (lrow >> 5) * 512 + p * 32 + (lrow & 31);   // global gate-col
      uint4 v = *(const uint4*)(Wg + (size_t)n * 512 + k16 * 8);
      int byte = lrow * 1024 + k16 * 16;
      *(uint4*)((char*)sW + (byte ^ ((lrow & 7) << 4))) = v;
    }
  }

  short8 zero8;
#pragma unroll
  for (int i = 0; i < 8; ++i) zero8[i] = 0;

  // per-thread swizzled byte bases for the two B n-tiles
  const int swz = (r0 & 7) << 4;
  const int wrow0 = (gate * 32 + r0) * 1024 + (khalf * 256 + k8) * 2;
  const int wrow1 = wrow0 + 16 * 1024;

  float cst0 = 0.f, cst1 = 0.f;           // this thread's two c values
  const int b_e = tid >> 4;               // epilogue batch row 0..31
  const int hc0 = (tid & 15) * 2;         // epilogue h-col pair base

  const ZT* Zb = Z + (size_t)dir * LSEQ * NB * NG + (size_t)b_e * NG + p * 32 + hc0;
  uint16_t* hb = hbuf + dir * 2 * NB * HH;
  int* tg = tags + dir * 256;             // 16 slots x 16 ints (64B stride)
  int* myslot = tg + p * 16;

  // Z prefetch for t=0 (HBM latency hides under W staging + first barrier)
  float2 vzi = zld2<ZT>(Zb);
  float2 vzg = zld2<ZT>(Zb + 512);
  float2 vzf = zld2<ZT>(Zb + 1024);
  float2 vzo = zld2<ZT>(Zb + 1536);

  __syncthreads();   // W panel staged

  for (int t = 0; t < LSEQ; ++t) {
    const uint32_t rm = dir ? rst[t] : 0u;

    if (t > 0) {
      if (wid == 0) {
        // wave 0 polls relaxed; lanes 0-15 each watch one 64B-strided slot.
        // No acquire needed: consumer h loads below bypass L1/L2 (sc0 sc1).
        int guard = 0;
        for (;;) {
          int v = t;
          if (lane < 16)
            v = __hip_atomic_load(tg + lane * 16, __ATOMIC_RELAXED,
                                  __HIP_MEMORY_SCOPE_AGENT);
          if (__all(v >= t)) break;
          __builtin_amdgcn_s_sleep(1);
          if (++guard > (1 << 14)) break;   // bounded anti-hang guard
        }
      }
      __syncthreads();   // B1: release all waves
    }

    // --- recurrent GEMM: gates_h = h @ Wh_panel ---
    // h via MALL-direct coalesced asm loads (no cache, no invalidate);
    // W B-fragments from swizzled LDS.
    const uint16_t* hA = hb + (t & 1) * NB * HH;
    const bool zr0 = (rm >> r0) & 1;
    const bool zr1 = (rm >> (16 + r0)) & 1;
    const int kof = khalf * 256 + k8;

    short8 a0[8], a1[8];
    {
      const uint16_t* pa = hA + (size_t)r0 * HH + kof;
#pragma unroll
      for (int kk = 0; kk < 8; ++kk) {
        a0[kk] = mload16(pa + kk * 32);
        a1[kk] = mload16(pa + 16 * HH + kk * 32);
      }
    }
    asm volatile("s_waitcnt vmcnt(0)" ::: "memory");
    __builtin_amdgcn_sched_barrier(0);
#pragma unroll
    for (int kk = 0; kk < 8; ++kk) {
      if (zr0) a0[kk] = zero8;           // ResetCore: h := 0 before step
      if (zr1) a1[kk] = zero8;
    }

    floatx4 acc[2][2];
#pragma unroll
    for (int m = 0; m < 2; ++m)
#pragma unroll
      for (int n = 0; n < 2; ++n)
#pragma unroll
        for (int r = 0; r < 4; ++r) acc[m][n][r] = 0.f;

#pragma unroll
    for (int kk = 0; kk < 8; ++kk) {
      short8 b0 = *(const short8*)((const char*)sW + ((wrow0 + kk * 64) ^ swz));
      short8 b1 = *(const short8*)((const char*)sW + ((wrow1 + kk * 64) ^ swz));
      acc[0][0] = __builtin_amdgcn_mfma_f32_16x16x32_bf16(a0[kk], b0, acc[0][0], 0, 0, 0);
      acc[0][1] = __builtin_amdgcn_mfma_f32_16x16x32_bf16(a0[kk], b1, acc[0][1], 0, 0, 0);
      acc[1][0] = __builtin_amdgcn_mfma_f32_16x16x32_bf16(a1[kk], b0, acc[1][0], 0, 0, 0);
      acc[1][1] = __builtin_amdgcn_mfma_f32_16x16x32_bf16(a1[kk], b1, acc[1][1], 0, 0, 0);
    }

    // partial sums: khalf0 writes, khalf1 accumulates in place
    if (khalf == 0) {
#pragma unroll
      for (int m = 0; m < 2; ++m)
#pragma unroll
        for (int n = 0; n < 2; ++n)
#pragma unroll
          for (int r = 0; r < 4; ++r) {
            int row = m * 16 + (lane >> 4) * 4 + r;
            sG[row * SGS + gate * 32 + n * 16 + r0] = acc[m][n][r];
          }
    }
    __syncthreads();   // B2
    if (khalf == 1) {
#pragma unroll
      for (int m = 0; m < 2; ++m)
#pragma unroll
        for (int n = 0; n < 2; ++n)
#pragma unroll
          for (int r = 0; r < 4; ++r) {
            int row = m * 16 + (lane >> 4) * 4 + r;
            sG[row * SGS + gate * 32 + n * 16 + r0] += acc[m][n][r];
          }
    }
    __syncthreads();   // B3

    // --- epilogue: gate nonlinearities + state update (2 outputs/thread) ---
    const int gb = b_e * SGS;
    const bool cz = (rm >> b_e) & 1;
    float hv0, hv1;
#pragma unroll
    for (int j = 0; j < 2; ++j) {
      int hc = hc0 + j;
      float xi = sG[gb + hc]      + (j ? vzi.y : vzi.x);
      float xg = sG[gb + 32 + hc] + (j ? vzg.y : vzg.x);
      float xf = sG[gb + 64 + hc] + (j ? vzf.y : vzf.x);
      float xo = sG[gb + 96 + hc] + (j ? vzo.y : vzo.x);
      float ii = fsigm(xi);
      float gg = ftanh(xg);
      float ff = fsigm(xf + 1.0f);   // haiku +1 forget-gate bias
      float oo = fsigm(xo);
      float cp = j ? cst1 : cst0;
      if (cz) cp = 0.f;              // ResetCore: c := 0 before step
      float cn = ff * cp + ii * gg;
      if (j) cst1 = cn; else cst0 = cn;
      float hn = oo * ftanh(cn);
      if (j) hv1 = hn; else hv0 = hn;
    }
    // stage h pair in LDS for the wide publish
    uint32_t hpack = (uint32_t)f2bf(hv0) | ((uint32_t)f2bf(hv1) << 16);
    *(uint32_t*)(sH + b_e * 32 + hc0) = hpack;
    __syncthreads();   // B4: sH complete (also fences sG reads vs next write)

    // wide MALL-direct publish: 128 threads x 16B
    if (tid < 128) {
      int row = tid >> 2, ch = tid & 3;
      uintx4 v = *(const uintx4*)(sH + row * 32 + ch * 8);
      mstore16(hb + ((t + 1) & 1) * NB * HH + (size_t)row * HH + p * 32 + ch * 8, v);
    }
    asm volatile("s_waitcnt vmcnt(0)" ::: "memory");
    __syncthreads();   // B5: all h stores drained before tag
    if (tid == 0)
      __hip_atomic_store(myslot, t + 1, __ATOMIC_RELAXED,
                         __HIP_MEMORY_SCOPE_AGENT);

    // Z prefetch for t+1 — HBM latency overlaps the next sync window
    if (t + 1 < LSEQ) {
      const ZT* zt = Zb + (size_t)(t + 1) * NB * NG;
      vzi = zld2<ZT>(zt);
      vzg = zld2<ZT>(zt + 512);
      vzf = zld2<ZT>(zt + 1024);
      vzo = zld2<ZT>(zt + 1536);
    }

    // fp32 output store AFTER the tag — HBM ack off the critical path
    const int t_x = dir ? (LSEQ - 1 - t) : t;
    float2 ov; ov.x = hv0; ov.y = hv1;
    *(float2*)(out + ((size_t)b_e * LSEQ + t_x) * 1024 + dir * 512 + p * 32 + hc0) = ov;
  }
}

// ---------------- diagnostic ----------------
__global__ void k_report(float* __restrict__ out, int n, float val)
{
  int tid = blockIdx.x * blockDim.x + threadIdx.x;
  int stride = gridDim.x * blockDim.x;
  for (int i = tid; i < n; i += stride) out[i] = val;
}

extern "C" void kernel_launch(void* const* d_in, const int* in_sizes, int n_in,
                              void* d_out, int out_size, void* d_ws, size_t ws_size,
                              hipStream_t stream)
{
  const float* x   = (const float*)d_in[0];
  const float* Wf  = (const float*)d_in[1];
  const float* bf_ = (const float*)d_in[2];
  const float* Wb  = (const float*)d_in[3];
  const float* bb_ = (const float*)d_in[4];
  const int*   len = (const int*)d_in[5];
  float* out = (float*)d_out;
  char* ws = (char*)d_ws;

  const bool f32z = ws_size >= WS_NEED_F32;
  if (!f32z && ws_size < WS_NEED_B16) {
    k_report<<<2048, 256, 0, stream>>>(out, out_size,
                                       200.0f + (float)(ws_size >> 20) * 0.1f);
    return;
  }

  uint16_t* WX  = (uint16_t*)(ws + WX_OFF);
  uint16_t* WHp = (uint16_t*)(ws + WH_OFF);
  uint16_t* X   = (uint16_t*)(ws + X_OFF);
  uint16_t* H   = (uint16_t*)(ws + H_OFF);
  uint32_t* RST = (uint32_t*)(ws + RST_OFF);
  int*      TAG = (int*)(ws + TAG_OFF);

  k_init<<<32, 256, 0, stream>>>(len, RST, TAG, H);
  k_wcast<<<4096, 256, 0, stream>>>(Wf, Wb, WX, WHp);
  k_xcast<<<16384, 256, 0, stream>>>(x, X);

  if (f32z) {
    float* Z = (float*)(ws + Z_OFF);
    k_zgemm<float><<<8192, 256, 0, stream>>>(X, WX, bf_, bb_, Z);
    k_rec<float><<<32, 512, 0, stream>>>(WHp, Z, RST, H, TAG, out);
  } else {
    uint16_t* Z = (uint16_t*)(ws + Z_OFF);
    k_zgemm<uint16_t><<<8192, 256, 0, stream>>>(X, WX, bf_, bb_, Z);
    k_rec<uint16_t><<<32, 512, 0, stream>>>(WHp, Z, RST, H, TAG, out);
  }
}

// Round 21
// 6576.053 us; speedup vs baseline: 1.1514x; 1.1514x over previous
//
#include <hip/hip_runtime.h>
#include <stdint.h>

// BiLSTM on MI355X — R21: FUSED persistent kernel, bf16 Z.
// R20 never ran: ws_size ~510 MiB < the 553 MiB fp32-Z layout (diagnostic
// value 251 decoded it). R4-R18 always used the bf16-Z path — restored here.
//   blocks 0-31   : recurrence (dir=bid>>4, panel=bid&15), exact R13 protocol
//                   + one extra poll lane gating on Z-tile readiness.
//   blocks 32-255 : GEMM workers, grid-stride over 8192 (dir,mtile,ntile)
//                   tiles in mtile order; Z stored as bf16 write-through
//                   (sc0 sc1), vmcnt drain, relaxed agent zready bump
//                   (the store->drain->flag pattern validated in R18).
// Backward dir: hk.ResetCore — state zeroed before flipped step t when
// t <= L - len[b]. OUTPUT IS FP32.

typedef __attribute__((ext_vector_type(8))) short  short8;
typedef __attribute__((ext_vector_type(4))) float  floatx4;

#define LSEQ 1024
#define NB   32
#define DD   512
#define HH   512
#define NG   2048

// ---- workspace layout (bytes) ----
#define WX_OFF  0ul                           // bf16 [dir][n][k]   4 MiB
#define WH_OFF  (4ul<<20)                     // bf16 [dir][n][k]   4 MiB
#define X_OFF   (8ul<<20)                     // bf16 [t][b][d]    32 MiB (unflipped)
#define H_OFF   (40ul<<20)                    // bf16 h ping-pong [dir][par][b][h] 256 KiB
#define RST_OFF ((40ul<<20)+(384ul<<10))      // u32 [1024]
#define TAG_OFF ((40ul<<20)+(388ul<<10))      // int [2][16][16] tags, 64B-strided
#define ZR_OFF  ((40ul<<20)+(392ul<<10))      // int [2][256][16] zready, 64B-strided (32 KiB)
#define Z_OFF   (41ul<<20)                    // bf16 [dir][step][b][n] 256 MiB
#define ZB_BYTES (2ul*LSEQ*NB*NG*2)
#define WS_NEED (Z_OFF + ZB_BYTES)            // ~297 MiB

__device__ inline uint16_t f2bf(float f) {
  uint32_t u = __float_as_uint(f);
  u += 0x7fff + ((u >> 16) & 1);              // RNE
  return (uint16_t)(u >> 16);
}
__device__ inline float fsigm(float x) { return 1.0f / (1.0f + __expf(-x)); }
__device__ inline float ftanh(float x) { return 1.0f - 2.0f / (__expf(2.0f * x) + 1.0f); }

// write-through (MALL-visible) bf16 store for Z (value in low 16 bits)
__device__ inline void zstore_wt(uint16_t* p, uint32_t v) {
  asm volatile("global_store_short %0, %1, off sc0 sc1"
               :: "v"(p), "v"(v) : "memory");
}
__device__ inline float2 zld2b(const uint16_t* p) {
  uint32_t u = *(const uint32_t*)p;
  float2 r;
  r.x = __uint_as_float((u & 0xffffu) << 16);
  r.y = __uint_as_float(u & 0xffff0000u);
  return r;
}

// ---------------- K0: init H, tags, zready, reset masks ----------------
__global__ void k_init(const int* __restrict__ len, uint32_t* __restrict__ rst,
                       int* __restrict__ tags, int* __restrict__ zr,
                       uint16_t* __restrict__ H)
{
  int tid = blockIdx.x * blockDim.x + threadIdx.x;
  int stride = gridDim.x * blockDim.x;
  for (int i = tid; i < 512; i += stride) tags[i] = 0;
  for (int i = tid; i < 2 * 256 * 16; i += stride) zr[i] = 0;
  for (int i = tid; i < 2 * 2 * NB * HH; i += stride) H[i] = 0;
  for (int t = tid; t < LSEQ; t += stride) {
    uint32_t m = 0;
    for (int b = 0; b < NB; ++b)
      m |= ((uint32_t)(t <= LSEQ - len[b])) << b;   // reset BEFORE flipped step t
    rst[t] = m;
  }
}

// ---------------- K1: W fp32 -> bf16, transpose to [n][k] ----------------
__global__ void k_wcast(const float* __restrict__ Wf, const float* __restrict__ Wb,
                        uint16_t* __restrict__ WX, uint16_t* __restrict__ WH)
{
  int tid = blockIdx.x * blockDim.x + threadIdx.x;   // [0, 2^20)
  if (tid >= 2 * 1024 * 512) return;
  int dir = tid >> 19;
  int r = tid & ((1 << 19) - 1);
  int k = r >> 9;                  // row of W (0..1023)
  int n4 = (r & 511) * 4;          // gate-col group
  const float* W = dir ? Wb : Wf;
  const float4 v = *(const float4*)(W + (size_t)k * NG + n4);
  uint16_t* dst;
  int kk;
  if (k < DD) { dst = WX + (size_t)dir * NG * DD; kk = k; }
  else        { dst = WH + (size_t)dir * NG * HH; kk = k - DD; }
  dst[(size_t)(n4 + 0) * 512 + kk] = f2bf(v.x);
  dst[(size_t)(n4 + 1) * 512 + kk] = f2bf(v.y);
  dst[(size_t)(n4 + 2) * 512 + kk] = f2bf(v.z);
  dst[(size_t)(n4 + 3) * 512 + kk] = f2bf(v.w);
}

// ---------------- K2: x fp32 -> bf16 time-major [t][b][d] ----------------
__global__ void k_xcast(const float* __restrict__ x, uint16_t* __restrict__ X)
{
  int i4 = blockIdx.x * blockDim.x + threadIdx.x;    // [0, 2^22)
  if (i4 >= (NB * LSEQ * DD) / 4) return;
  int d4 = (i4 & 127) * 4;
  int t  = (i4 >> 7) & 1023;
  int b  = i4 >> 17;
  const float4 v = *(const float4*)(x + (size_t)i4 * 4);
  uint32_t lo = (uint32_t)f2bf(v.x) | ((uint32_t)f2bf(v.y) << 16);
  uint32_t hi = (uint32_t)f2bf(v.z) | ((uint32_t)f2bf(v.w) << 16);
  uint2 u; u.x = lo; u.y = hi;
  *(uint2*)(X + ((size_t)t * NB + b) * DD + d4) = u;
}

// ---------------- K3: fused persistent kernel ----------------
// grid = 256 WGs x 512 threads, 1 WG/CU (144 KB LDS).
__global__ __launch_bounds__(512, 2) void k_rec(
    const uint16_t* __restrict__ WH, const uint16_t* __restrict__ WX,
    const uint16_t* __restrict__ X, uint16_t* __restrict__ Z,
    const float* __restrict__ bf_, const float* __restrict__ bb_,
    const uint32_t* __restrict__ rst, uint16_t* __restrict__ hbuf,
    int* __restrict__ tags, int* __restrict__ zready,
    float* __restrict__ out)
{
  __shared__ uint16_t sW[128 * 512];   // 128 KB: rec W panel / gemm tiles
  __shared__ float sG[NB * 128];       // 16 KB gate sums [b][gate*32+col]

  const int bid = blockIdx.x;
  const int tid = threadIdx.x;
  const int lane = tid & 63;
  const int wid = tid >> 6;

  if (bid >= 32) {
    // ================= GEMM worker role =================
    uint16_t* sA = sW;                  // 128x32 bf16 tile
    uint16_t* sB = sW + 128 * 32;
    const int wm = (wid >> 2) * 64;     // 2 row-halves x 4 col-quads
    const int wn = (wid & 3) * 32;

    for (int tau = bid - 32; tau < 8192; tau += 224) {
      const int mtile = tau >> 5;
      const int rem = tau & 31;
      const int dir = rem >> 4;
      const int ntile = rem & 15;

      const uint16_t* B = WX + (size_t)dir * NG * 512 + (size_t)(ntile * 128) * 512;
      const float* bias = (dir ? bb_ : bf_) + ntile * 128;

      uint4 ra, rb;
      auto load_tile = [&](int kk) {
        int row = tid >> 2, ko = (tid & 3) * 8;
        int grow = mtile * 128 + row;
        int step = grow >> 5, bb = grow & 31;
        int srow = dir ? ((1023 - step) * 32 + bb) : grow;   // flip time for bwd
        ra = *(const uint4*)(X + (size_t)srow * 512 + kk * 32 + ko);
        rb = *(const uint4*)(B + (size_t)row * 512 + kk * 32 + ko);
      };
      auto write_tile = [&]() {
        int row = tid >> 2, ko = (tid & 3) * 8;
        *(uint4*)(sA + row * 32 + ko) = ra;
        *(uint4*)(sB + row * 32 + ko) = rb;
      };

      floatx4 acc[4][2];
#pragma unroll
      for (int m = 0; m < 4; ++m)
#pragma unroll
        for (int n = 0; n < 2; ++n)
#pragma unroll
          for (int r = 0; r < 4; ++r) acc[m][n][r] = 0.f;

      load_tile(0);
      for (int kk = 0; kk < 16; ++kk) {
        __syncthreads();
        write_tile();
        __syncthreads();
        if (kk < 15) load_tile(kk + 1);
        short8 af[4], bb8[2];
#pragma unroll
        for (int m = 0; m < 4; ++m)
          af[m] = *(const short8*)(sA + (wm + m * 16 + (lane & 15)) * 32 + (lane >> 4) * 8);
#pragma unroll
        for (int n = 0; n < 2; ++n)
          bb8[n] = *(const short8*)(sB + (wn + n * 16 + (lane & 15)) * 32 + (lane >> 4) * 8);
#pragma unroll
        for (int m = 0; m < 4; ++m)
#pragma unroll
          for (int n = 0; n < 2; ++n)
            acc[m][n] = __builtin_amdgcn_mfma_f32_16x16x32_bf16(af[m], bb8[n], acc[m][n], 0, 0, 0);
      }

      uint16_t* Zo = Z + ((size_t)dir * 32768 + (size_t)mtile * 128) * 2048 + ntile * 128;
#pragma unroll
      for (int n = 0; n < 2; ++n) {
        int col = wn + n * 16 + (lane & 15);
        float bv = bias[col];
#pragma unroll
        for (int m = 0; m < 4; ++m) {
          int row0 = wm + m * 16 + (lane >> 4) * 4;
#pragma unroll
          for (int r = 0; r < 4; ++r)
            zstore_wt(Zo + (size_t)(row0 + r) * 2048 + col,
                      (uint32_t)f2bf(acc[m][n][r] + bv));
        }
      }
      asm volatile("s_waitcnt vmcnt(0)" ::: "memory");
      __syncthreads();   // all waves' Z stores drained
      if (tid == 0)
        __hip_atomic_fetch_add(zready + ((size_t)dir * 256 + mtile) * 16, 1,
                               __ATOMIC_RELAXED, __HIP_MEMORY_SCOPE_AGENT);
    }
    return;
  }

  // ================= recurrence role (exact R13 protocol) =================
  const int gate = wid & 3;
  const int khalf = wid >> 2;
  const int dir = bid >> 4;
  const int p = bid & 15;
  const int r0 = lane & 15;
  const int k8 = (lane >> 4) * 8;

  // stage W_h panel into LDS once (XOR-swizzled rows)
  {
    const uint16_t* Wg = WH + (size_t)dir * NG * HH;
    for (int i = tid; i < 8192; i += 512) {
      int lrow = i >> 6;
      int k16  = i & 63;
      int n = (lrow >> 5) * 512 + p * 32 + (lrow & 31);
      uint4 v = *(const uint4*)(Wg + (size_t)n * 512 + k16 * 8);
      int byte = lrow * 1024 + k16 * 16;
      *(uint4*)((char*)sW + (byte ^ ((lrow & 7) << 4))) = v;
    }
  }

  short8 zero8;
#pragma unroll
  for (int i = 0; i < 8; ++i) zero8[i] = 0;

  const int swz = (r0 & 7) << 4;
  const int wrow0 = (gate * 32 + r0) * 1024 + (khalf * 256 + k8) * 2;
  const int wrow1 = wrow0 + 16 * 1024;

  float cst0 = 0.f, cst1 = 0.f;
  const int b_e = tid >> 4;
  const int hc0 = (tid & 15) * 2;

  const uint16_t* Zb = Z + (size_t)dir * LSEQ * NB * NG + (size_t)b_e * NG + p * 32 + hc0;
  uint16_t* hb = hbuf + dir * 2 * NB * HH;
  int* tg = tags + dir * 256;
  int* myslot = tg + p * 16;
  const int* zrd = zready + (size_t)dir * 256 * 16;

  __syncthreads();   // W panel staged

  for (int t = 0; t < LSEQ; ++t) {
    const uint32_t rm = dir ? rst[t] : 0u;

    // poll: lanes 0-15 watch producer tags; lane 16 gates Z readiness
    if (wid == 0) {
      const int mt = t >> 2;
      int guard = 0;
      for (;;) {
        int ok = 1;
        if (lane < 16)
          ok = __hip_atomic_load(tg + lane * 16, __ATOMIC_RELAXED,
                                 __HIP_MEMORY_SCOPE_AGENT) >= t;
        else if (lane == 16)
          ok = __hip_atomic_load(zrd + mt * 16, __ATOMIC_RELAXED,
                                 __HIP_MEMORY_SCOPE_AGENT) >= 16;
        if (__all(ok)) break;
        __builtin_amdgcn_s_sleep(1);
        if (++guard > (1 << 15)) break;   // bounded anti-hang guard
      }
      // ONE acquire: L1/L2 invalidate so plain cached h/Z loads are fresh
      if (lane < 16)
        (void)__hip_atomic_load(tg + lane * 16, __ATOMIC_ACQUIRE,
                                __HIP_MEMORY_SCOPE_AGENT);
    }
    __syncthreads();   // B1

    // Z loads (plain cached, post-inv; slack until epilogue)
    const uint16_t* zt = Zb + (size_t)t * NB * NG;
    float2 vzi = zld2b(zt);
    float2 vzg = zld2b(zt + 512);
    float2 vzf = zld2b(zt + 1024);
    float2 vzo = zld2b(zt + 1536);

    // --- recurrent GEMM: gates_h = h @ Wh_panel ---
    const uint16_t* hA = hb + (t & 1) * NB * HH;
    const bool zr0 = (rm >> r0) & 1;
    const bool zr1 = (rm >> (16 + r0)) & 1;
    const int kof = khalf * 256 + k8;

    floatx4 acc[2][2];
#pragma unroll
    for (int m = 0; m < 2; ++m)
#pragma unroll
      for (int n = 0; n < 2; ++n)
#pragma unroll
        for (int r = 0; r < 4; ++r) acc[m][n][r] = 0.f;

#pragma unroll
    for (int kk = 0; kk < 8; ++kk) {
      short8 a0 = *(const short8*)(hA + (size_t)r0 * HH + kof + kk * 32);
      short8 a1 = *(const short8*)(hA + (size_t)(16 + r0) * HH + kof + kk * 32);
      if (zr0) a0 = zero8;               // ResetCore: h := 0 before step
      if (zr1) a1 = zero8;
      short8 b0 = *(const short8*)((const char*)sW + ((wrow0 + kk * 64) ^ swz));
      short8 b1 = *(const short8*)((const char*)sW + ((wrow1 + kk * 64) ^ swz));
      acc[0][0] = __builtin_amdgcn_mfma_f32_16x16x32_bf16(a0, b0, acc[0][0], 0, 0, 0);
      acc[0][1] = __builtin_amdgcn_mfma_f32_16x16x32_bf16(a0, b1, acc[0][1], 0, 0, 0);
      acc[1][0] = __builtin_amdgcn_mfma_f32_16x16x32_bf16(a1, b0, acc[1][0], 0, 0, 0);
      acc[1][1] = __builtin_amdgcn_mfma_f32_16x16x32_bf16(a1, b1, acc[1][1], 0, 0, 0);
    }

    // partial sums: khalf0 writes, khalf1 accumulates in place
    if (khalf == 0) {
#pragma unroll
      for (int m = 0; m < 2; ++m)
#pragma unroll
        for (int n = 0; n < 2; ++n)
#pragma unroll
          for (int r = 0; r < 4; ++r) {
            int row = m * 16 + (lane >> 4) * 4 + r;
            sG[row * 128 + gate * 32 + n * 16 + r0] = acc[m][n][r];
          }
    }
    __syncthreads();   // B2
    if (khalf == 1) {
#pragma unroll
      for (int m = 0; m < 2; ++m)
#pragma unroll
        for (int n = 0; n < 2; ++n)
#pragma unroll
          for (int r = 0; r < 4; ++r) {
            int row = m * 16 + (lane >> 4) * 4 + r;
            sG[row * 128 + gate * 32 + n * 16 + r0] += acc[m][n][r];
          }
    }
    __syncthreads();   // B3

    // --- epilogue: gate nonlinearities + state update (2 outputs/thread) ---
    const int gb = b_e * 128;
    const bool cz = (rm >> b_e) & 1;
    float hv0, hv1;
#pragma unroll
    for (int j = 0; j < 2; ++j) {
      int hc = hc0 + j;
      float xi = sG[gb + hc]      + (j ? vzi.y : vzi.x);
      float xg = sG[gb + 32 + hc] + (j ? vzg.y : vzg.x);
      float xf = sG[gb + 64 + hc] + (j ? vzf.y : vzf.x);
      float xo = sG[gb + 96 + hc] + (j ? vzo.y : vzo.x);
      float ii = fsigm(xi);
      float gg = ftanh(xg);
      float ff = fsigm(xf + 1.0f);   // haiku +1 forget-gate bias
      float oo = fsigm(xo);
      float cp = j ? cst1 : cst0;
      if (cz) cp = 0.f;              // ResetCore: c := 0 before step
      float cn = ff * cp + ii * gg;
      if (j) cst1 = cn; else cst0 = cn;
      float hn = oo * ftanh(cn);
      if (j) hv1 = hn; else hv0 = hn;
    }
    // publish bf16 h coherently (agent write-through)
    uint32_t hpack = (uint32_t)f2bf(hv0) | ((uint32_t)f2bf(hv1) << 16);
    __hip_atomic_store(
        (uint32_t*)(hb + ((t + 1) & 1) * NB * HH + (size_t)b_e * HH + p * 32 + hc0),
        hpack, __ATOMIC_RELAXED, __HIP_MEMORY_SCOPE_AGENT);

    asm volatile("s_waitcnt vmcnt(0)" ::: "memory");
    __syncthreads();   // B4: all h publishes drained before tag
    if (tid == 0)
      __hip_atomic_store(myslot, t + 1, __ATOMIC_RELAXED,
                         __HIP_MEMORY_SCOPE_AGENT);

    // fp32 output store AFTER the tag — HBM ack off the critical path
    const int t_x = dir ? (LSEQ - 1 - t) : t;
    float2 ov; ov.x = hv0; ov.y = hv1;
    *(float2*)(out + ((size_t)b_e * LSEQ + t_x) * 1024 + dir * 512 + p * 32 + hc0) = ov;
  }
}

// ---------------- diagnostic ----------------
__global__ void k_report(float* __restrict__ out, int n, float val)
{
  int tid = blockIdx.x * blockDim.x + threadIdx.x;
  int stride = gridDim.x * blockDim.x;
  for (int i = tid; i < n; i += stride) out[i] = val;
}

extern "C" void kernel_launch(void* const* d_in, const int* in_sizes, int n_in,
                              void* d_out, int out_size, void* d_ws, size_t ws_size,
                              hipStream_t stream)
{
  const float* x   = (const float*)d_in[0];
  const float* Wf  = (const float*)d_in[1];
  const float* bf_ = (const float*)d_in[2];
  const float* Wb  = (const float*)d_in[3];
  const float* bb_ = (const float*)d_in[4];
  const int*   len = (const int*)d_in[5];
  float* out = (float*)d_out;
  char* ws = (char*)d_ws;

  if (ws_size < WS_NEED) {
    k_report<<<2048, 256, 0, stream>>>(out, out_size,
                                       200.0f + (float)(ws_size >> 20) * 0.1f);
    return;
  }

  uint16_t* WX  = (uint16_t*)(ws + WX_OFF);
  uint16_t* WHp = (uint16_t*)(ws + WH_OFF);
  uint16_t* X   = (uint16_t*)(ws + X_OFF);
  uint16_t* H   = (uint16_t*)(ws + H_OFF);
  uint32_t* RST = (uint32_t*)(ws + RST_OFF);
  int*      TAG = (int*)(ws + TAG_OFF);
  int*      ZR  = (int*)(ws + ZR_OFF);
  uint16_t* Z   = (uint16_t*)(ws + Z_OFF);

  k_init<<<64, 256, 0, stream>>>(len, RST, TAG, ZR, H);
  k_wcast<<<4096, 256, 0, stream>>>(Wf, Wb, WX, WHp);
  k_xcast<<<16384, 256, 0, stream>>>(x, X);
  k_rec<<<256, 512, 0, stream>>>(WHp, WX, X, Z, bf_, bb_, RST, H, TAG, ZR, out);
}

// Round 22
// 6569.363 us; speedup vs baseline: 1.1526x; 1.0010x over previous
//
#include <hip/hip_runtime.h>
#include <stdint.h>

// BiLSTM on MI355X — R22: R21 (passing, 6.58 ms) + CLOCK-KEEPER spinners.
// Hypothesis under test: at ~2% activity the engine clock is DVFS'd ~2.5x
// below boost, inflating every latency in the per-step sync chain (explains
// the 3x model-vs-measured gap AND six null micro-probes R15-R18).
// GEMM workers (blocks 32-255), after finishing their Z tiles, spin on a
// real VALU FMA chain until all 32 recurrence WGs bump a done counter —
// keeping 224 CUs hot so utilization-driven DVFS holds boost clocks.
// Everything else identical to R21:
//   blocks 0-31   : recurrence (dir=bid>>4, panel=bid&15), R13 protocol
//                   + poll lane gating on Z-tile readiness.
//   blocks 32-255 : GEMM workers, grid-stride over 8192 tiles, bf16 Z
//                   write-through + vmcnt drain + zready bump.
// Backward dir: hk.ResetCore — state zeroed before flipped step t when
// t <= L - len[b]. OUTPUT IS FP32.

typedef __attribute__((ext_vector_type(8))) short  short8;
typedef __attribute__((ext_vector_type(4))) float  floatx4;

#define LSEQ 1024
#define NB   32
#define DD   512
#define HH   512
#define NG   2048

// ---- workspace layout (bytes) ----
#define WX_OFF  0ul                           // bf16 [dir][n][k]   4 MiB
#define WH_OFF  (4ul<<20)                     // bf16 [dir][n][k]   4 MiB
#define X_OFF   (8ul<<20)                     // bf16 [t][b][d]    32 MiB (unflipped)
#define H_OFF   (40ul<<20)                    // bf16 h ping-pong [dir][par][b][h] 256 KiB
#define RST_OFF ((40ul<<20)+(384ul<<10))      // u32 [1024]
#define TAG_OFF ((40ul<<20)+(388ul<<10))      // int [2][16][16] tags, 64B-strided
#define ZR_OFF  ((40ul<<20)+(392ul<<10))      // int [2][256][16] zready (32 KiB)
#define DONE_OFF ((40ul<<20)+(424ul<<10))     // int [16] done counter slot
#define Z_OFF   (41ul<<20)                    // bf16 [dir][step][b][n] 256 MiB
#define ZB_BYTES (2ul*LSEQ*NB*NG*2)
#define WS_NEED (Z_OFF + ZB_BYTES)            // ~297 MiB

__device__ inline uint16_t f2bf(float f) {
  uint32_t u = __float_as_uint(f);
  u += 0x7fff + ((u >> 16) & 1);              // RNE
  return (uint16_t)(u >> 16);
}
__device__ inline float fsigm(float x) { return 1.0f / (1.0f + __expf(-x)); }
__device__ inline float ftanh(float x) { return 1.0f - 2.0f / (__expf(2.0f * x) + 1.0f); }

// write-through (MALL-visible) bf16 store for Z (value in low 16 bits)
__device__ inline void zstore_wt(uint16_t* p, uint32_t v) {
  asm volatile("global_store_short %0, %1, off sc0 sc1"
               :: "v"(p), "v"(v) : "memory");
}
__device__ inline float2 zld2b(const uint16_t* p) {
  uint32_t u = *(const uint32_t*)p;
  float2 r;
  r.x = __uint_as_float((u & 0xffffu) << 16);
  r.y = __uint_as_float(u & 0xffff0000u);
  return r;
}

// ---------------- K0: init H, tags, zready, done, reset masks ----------------
__global__ void k_init(const int* __restrict__ len, uint32_t* __restrict__ rst,
                       int* __restrict__ tags, int* __restrict__ zr,
                       int* __restrict__ dn, uint16_t* __restrict__ H)
{
  int tid = blockIdx.x * blockDim.x + threadIdx.x;
  int stride = gridDim.x * blockDim.x;
  for (int i = tid; i < 512; i += stride) tags[i] = 0;
  for (int i = tid; i < 2 * 256 * 16; i += stride) zr[i] = 0;
  for (int i = tid; i < 16; i += stride) dn[i] = 0;
  for (int i = tid; i < 2 * 2 * NB * HH; i += stride) H[i] = 0;
  for (int t = tid; t < LSEQ; t += stride) {
    uint32_t m = 0;
    for (int b = 0; b < NB; ++b)
      m |= ((uint32_t)(t <= LSEQ - len[b])) << b;   // reset BEFORE flipped step t
    rst[t] = m;
  }
}

// ---------------- K1: W fp32 -> bf16, transpose to [n][k] ----------------
__global__ void k_wcast(const float* __restrict__ Wf, const float* __restrict__ Wb,
                        uint16_t* __restrict__ WX, uint16_t* __restrict__ WH)
{
  int tid = blockIdx.x * blockDim.x + threadIdx.x;   // [0, 2^20)
  if (tid >= 2 * 1024 * 512) return;
  int dir = tid >> 19;
  int r = tid & ((1 << 19) - 1);
  int k = r >> 9;                  // row of W (0..1023)
  int n4 = (r & 511) * 4;          // gate-col group
  const float* W = dir ? Wb : Wf;
  const float4 v = *(const float4*)(W + (size_t)k * NG + n4);
  uint16_t* dst;
  int kk;
  if (k < DD) { dst = WX + (size_t)dir * NG * DD; kk = k; }
  else        { dst = WH + (size_t)dir * NG * HH; kk = k - DD; }
  dst[(size_t)(n4 + 0) * 512 + kk] = f2bf(v.x);
  dst[(size_t)(n4 + 1) * 512 + kk] = f2bf(v.y);
  dst[(size_t)(n4 + 2) * 512 + kk] = f2bf(v.z);
  dst[(size_t)(n4 + 3) * 512 + kk] = f2bf(v.w);
}

// ---------------- K2: x fp32 -> bf16 time-major [t][b][d] ----------------
__global__ void k_xcast(const float* __restrict__ x, uint16_t* __restrict__ X)
{
  int i4 = blockIdx.x * blockDim.x + threadIdx.x;    // [0, 2^22)
  if (i4 >= (NB * LSEQ * DD) / 4) return;
  int d4 = (i4 & 127) * 4;
  int t  = (i4 >> 7) & 1023;
  int b  = i4 >> 17;
  const float4 v = *(const float4*)(x + (size_t)i4 * 4);
  uint32_t lo = (uint32_t)f2bf(v.x) | ((uint32_t)f2bf(v.y) << 16);
  uint32_t hi = (uint32_t)f2bf(v.z) | ((uint32_t)f2bf(v.w) << 16);
  uint2 u; u.x = lo; u.y = hi;
  *(uint2*)(X + ((size_t)t * NB + b) * DD + d4) = u;
}

// ---------------- K3: fused persistent kernel ----------------
// grid = 256 WGs x 512 threads, 1 WG/CU (144 KB LDS).
__global__ __launch_bounds__(512, 2) void k_rec(
    const uint16_t* __restrict__ WH, const uint16_t* __restrict__ WX,
    const uint16_t* __restrict__ X, uint16_t* __restrict__ Z,
    const float* __restrict__ bf_, const float* __restrict__ bb_,
    const uint32_t* __restrict__ rst, uint16_t* __restrict__ hbuf,
    int* __restrict__ tags, int* __restrict__ zready,
    int* __restrict__ done, float* __restrict__ out)
{
  __shared__ uint16_t sW[128 * 512];   // 128 KB: rec W panel / gemm tiles
  __shared__ float sG[NB * 128];       // 16 KB gate sums [b][gate*32+col]

  const int bid = blockIdx.x;
  const int tid = threadIdx.x;
  const int lane = tid & 63;
  const int wid = tid >> 6;

  if (bid >= 32) {
    // ================= GEMM worker role =================
    uint16_t* sA = sW;                  // 128x32 bf16 tile
    uint16_t* sB = sW + 128 * 32;
    const int wm = (wid >> 2) * 64;     // 2 row-halves x 4 col-quads
    const int wn = (wid & 3) * 32;

    for (int tau = bid - 32; tau < 8192; tau += 224) {
      const int mtile = tau >> 5;
      const int rem = tau & 31;
      const int dir = rem >> 4;
      const int ntile = rem & 15;

      const uint16_t* B = WX + (size_t)dir * NG * 512 + (size_t)(ntile * 128) * 512;
      const float* bias = (dir ? bb_ : bf_) + ntile * 128;

      uint4 ra, rb;
      auto load_tile = [&](int kk) {
        int row = tid >> 2, ko = (tid & 3) * 8;
        int grow = mtile * 128 + row;
        int step = grow >> 5, bb = grow & 31;
        int srow = dir ? ((1023 - step) * 32 + bb) : grow;   // flip time for bwd
        ra = *(const uint4*)(X + (size_t)srow * 512 + kk * 32 + ko);
        rb = *(const uint4*)(B + (size_t)row * 512 + kk * 32 + ko);
      };
      auto write_tile = [&]() {
        int row = tid >> 2, ko = (tid & 3) * 8;
        *(uint4*)(sA + row * 32 + ko) = ra;
        *(uint4*)(sB + row * 32 + ko) = rb;
      };

      floatx4 acc[4][2];
#pragma unroll
      for (int m = 0; m < 4; ++m)
#pragma unroll
        for (int n = 0; n < 2; ++n)
#pragma unroll
          for (int r = 0; r < 4; ++r) acc[m][n][r] = 0.f;

      load_tile(0);
      for (int kk = 0; kk < 16; ++kk) {
        __syncthreads();
        write_tile();
        __syncthreads();
        if (kk < 15) load_tile(kk + 1);
        short8 af[4], bb8[2];
#pragma unroll
        for (int m = 0; m < 4; ++m)
          af[m] = *(const short8*)(sA + (wm + m * 16 + (lane & 15)) * 32 + (lane >> 4) * 8);
#pragma unroll
        for (int n = 0; n < 2; ++n)
          bb8[n] = *(const short8*)(sB + (wn + n * 16 + (lane & 15)) * 32 + (lane >> 4) * 8);
#pragma unroll
        for (int m = 0; m < 4; ++m)
#pragma unroll
          for (int n = 0; n < 2; ++n)
            acc[m][n] = __builtin_amdgcn_mfma_f32_16x16x32_bf16(af[m], bb8[n], acc[m][n], 0, 0, 0);
      }

      uint16_t* Zo = Z + ((size_t)dir * 32768 + (size_t)mtile * 128) * 2048 + ntile * 128;
#pragma unroll
      for (int n = 0; n < 2; ++n) {
        int col = wn + n * 16 + (lane & 15);
        float bv = bias[col];
#pragma unroll
        for (int m = 0; m < 4; ++m) {
          int row0 = wm + m * 16 + (lane >> 4) * 4;
#pragma unroll
          for (int r = 0; r < 4; ++r)
            zstore_wt(Zo + (size_t)(row0 + r) * 2048 + col,
                      (uint32_t)f2bf(acc[m][n][r] + bv));
        }
      }
      asm volatile("s_waitcnt vmcnt(0)" ::: "memory");
      __syncthreads();   // all waves' Z stores drained
      if (tid == 0)
        __hip_atomic_fetch_add(zready + ((size_t)dir * 256 + mtile) * 16, 1,
                               __ATOMIC_RELAXED, __HIP_MEMORY_SCOPE_AGENT);
    }

    // ---- CLOCK-KEEPER: stay hot until all 32 recurrence WGs are done ----
    volatile int* sflag = (volatile int*)sG;
    __syncthreads();
    if (tid == 0) *sflag = 0;
    __syncthreads();
    float kacc = (float)tid * 0.001f + 1.0f;
    int guard = 0;
    for (;;) {
#pragma unroll
      for (int i = 0; i < 256; ++i)
        kacc = __builtin_fmaf(kacc, 1.0000001f, 0.0000001f);
      asm volatile("" : "+v"(kacc));        // keep the FMA chain live
      if (tid == 0) {
        if (__hip_atomic_load(done, __ATOMIC_RELAXED,
                              __HIP_MEMORY_SCOPE_AGENT) >= 32)
          *sflag = 1;
      }
      if (*sflag) break;
      if (++guard > (1 << 16)) break;       // bounded (~30 ms worst case)
    }
    return;
  }

  // ================= recurrence role (exact R13 protocol) =================
  const int gate = wid & 3;
  const int khalf = wid >> 2;
  const int dir = bid >> 4;
  const int p = bid & 15;
  const int r0 = lane & 15;
  const int k8 = (lane >> 4) * 8;

  // stage W_h panel into LDS once (XOR-swizzled rows)
  {
    const uint16_t* Wg = WH + (size_t)dir * NG * HH;
    for (int i = tid; i < 8192; i += 512) {
      int lrow = i >> 6;
      int k16  = i & 63;
      int n = (lrow >> 5) * 512 + p * 32 + (lrow & 31);
      uint4 v = *(const uint4*)(Wg + (size_t)n * 512 + k16 * 8);
      int byte = lrow * 1024 + k16 * 16;
      *(uint4*)((char*)sW + (byte ^ ((lrow & 7) << 4))) = v;
    }
  }

  short8 zero8;
#pragma unroll
  for (int i = 0; i < 8; ++i) zero8[i] = 0;

  const int swz = (r0 & 7) << 4;
  const int wrow0 = (gate * 32 + r0) * 1024 + (khalf * 256 + k8) * 2;
  const int wrow1 = wrow0 + 16 * 1024;

  float cst0 = 0.f, cst1 = 0.f;
  const int b_e = tid >> 4;
  const int hc0 = (tid & 15) * 2;

  const uint16_t* Zb = Z + (size_t)dir * LSEQ * NB * NG + (size_t)b_e * NG + p * 32 + hc0;
  uint16_t* hb = hbuf + dir * 2 * NB * HH;
  int* tg = tags + dir * 256;
  int* myslot = tg + p * 16;
  const int* zrd = zready + (size_t)dir * 256 * 16;

  __syncthreads();   // W panel staged

  for (int t = 0; t < LSEQ; ++t) {
    const uint32_t rm = dir ? rst[t] : 0u;

    // poll: lanes 0-15 watch producer tags; lane 16 gates Z readiness
    if (wid == 0) {
      const int mt = t >> 2;
      int guard = 0;
      for (;;) {
        int ok = 1;
        if (lane < 16)
          ok = __hip_atomic_load(tg + lane * 16, __ATOMIC_RELAXED,
                                 __HIP_MEMORY_SCOPE_AGENT) >= t;
        else if (lane == 16)
          ok = __hip_atomic_load(zrd + mt * 16, __ATOMIC_RELAXED,
                                 __HIP_MEMORY_SCOPE_AGENT) >= 16;
        if (__all(ok)) break;
        __builtin_amdgcn_s_sleep(1);
        if (++guard > (1 << 15)) break;   // bounded anti-hang guard
      }
      // ONE acquire: L1/L2 invalidate so plain cached h/Z loads are fresh
      if (lane < 16)
        (void)__hip_atomic_load(tg + lane * 16, __ATOMIC_ACQUIRE,
                                __HIP_MEMORY_SCOPE_AGENT);
    }
    __syncthreads();   // B1

    // Z loads (plain cached, post-inv; slack until epilogue)
    const uint16_t* zt = Zb + (size_t)t * NB * NG;
    float2 vzi = zld2b(zt);
    float2 vzg = zld2b(zt + 512);
    float2 vzf = zld2b(zt + 1024);
    float2 vzo = zld2b(zt + 1536);

    // --- recurrent GEMM: gates_h = h @ Wh_panel ---
    const uint16_t* hA = hb + (t & 1) * NB * HH;
    const bool zr0 = (rm >> r0) & 1;
    const bool zr1 = (rm >> (16 + r0)) & 1;
    const int kof = khalf * 256 + k8;

    floatx4 acc[2][2];
#pragma unroll
    for (int m = 0; m < 2; ++m)
#pragma unroll
      for (int n = 0; n < 2; ++n)
#pragma unroll
        for (int r = 0; r < 4; ++r) acc[m][n][r] = 0.f;

#pragma unroll
    for (int kk = 0; kk < 8; ++kk) {
      short8 a0 = *(const short8*)(hA + (size_t)r0 * HH + kof + kk * 32);
      short8 a1 = *(const short8*)(hA + (size_t)(16 + r0) * HH + kof + kk * 32);
      if (zr0) a0 = zero8;               // ResetCore: h := 0 before step
      if (zr1) a1 = zero8;
      short8 b0 = *(const short8*)((const char*)sW + ((wrow0 + kk * 64) ^ swz));
      short8 b1 = *(const short8*)((const char*)sW + ((wrow1 + kk * 64) ^ swz));
      acc[0][0] = __builtin_amdgcn_mfma_f32_16x16x32_bf16(a0, b0, acc[0][0], 0, 0, 0);
      acc[0][1] = __builtin_amdgcn_mfma_f32_16x16x32_bf16(a0, b1, acc[0][1], 0, 0, 0);
      acc[1][0] = __builtin_amdgcn_mfma_f32_16x16x32_bf16(a1, b0, acc[1][0], 0, 0, 0);
      acc[1][1] = __builtin_amdgcn_mfma_f32_16x16x32_bf16(a1, b1, acc[1][1], 0, 0, 0);
    }

    // partial sums: khalf0 writes, khalf1 accumulates in place
    if (khalf == 0) {
#pragma unroll
      for (int m = 0; m < 2; ++m)
#pragma unroll
        for (int n = 0; n < 2; ++n)
#pragma unroll
          for (int r = 0; r < 4; ++r) {
            int row = m * 16 + (lane >> 4) * 4 + r;
            sG[row * 128 + gate * 32 + n * 16 + r0] = acc[m][n][r];
          }
    }
    __syncthreads();   // B2
    if (khalf == 1) {
#pragma unroll
      for (int m = 0; m < 2; ++m)
#pragma unroll
        for (int n = 0; n < 2; ++n)
#pragma unroll
          for (int r = 0; r < 4; ++r) {
            int row = m * 16 + (lane >> 4) * 4 + r;
            sG[row * 128 + gate * 32 + n * 16 + r0] += acc[m][n][r];
          }
    }
    __syncthreads();   // B3

    // --- epilogue: gate nonlinearities + state update (2 outputs/thread) ---
    const int gb = b_e * 128;
    const bool cz = (rm >> b_e) & 1;
    float hv0, hv1;
#pragma unroll
    for (int j = 0; j < 2; ++j) {
      int hc = hc0 + j;
      float xi = sG[gb + hc]      + (j ? vzi.y : vzi.x);
      float xg = sG[gb + 32 + hc] + (j ? vzg.y : vzg.x);
      float xf = sG[gb + 64 + hc] + (j ? vzf.y : vzf.x);
      float xo = sG[gb + 96 + hc] + (j ? vzo.y : vzo.x);
      float ii = fsigm(xi);
      float gg = ftanh(xg);
      float ff = fsigm(xf + 1.0f);   // haiku +1 forget-gate bias
      float oo = fsigm(xo);
      float cp = j ? cst1 : cst0;
      if (cz) cp = 0.f;              // ResetCore: c := 0 before step
      float cn = ff * cp + ii * gg;
      if (j) cst1 = cn; else cst0 = cn;
      float hn = oo * ftanh(cn);
      if (j) hv1 = hn; else hv0 = hn;
    }
    // publish bf16 h coherently (agent write-through)
    uint32_t hpack = (uint32_t)f2bf(hv0) | ((uint32_t)f2bf(hv1) << 16);
    __hip_atomic_store(
        (uint32_t*)(hb + ((t + 1) & 1) * NB * HH + (size_t)b_e * HH + p * 32 + hc0),
        hpack, __ATOMIC_RELAXED, __HIP_MEMORY_SCOPE_AGENT);

    asm volatile("s_waitcnt vmcnt(0)" ::: "memory");
    __syncthreads();   // B4: all h publishes drained before tag
    if (tid == 0)
      __hip_atomic_store(myslot, t + 1, __ATOMIC_RELAXED,
                         __HIP_MEMORY_SCOPE_AGENT);

    // fp32 output store AFTER the tag — HBM ack off the critical path
    const int t_x = dir ? (LSEQ - 1 - t) : t;
    float2 ov; ov.x = hv0; ov.y = hv1;
    *(float2*)(out + ((size_t)b_e * LSEQ + t_x) * 1024 + dir * 512 + p * 32 + hc0) = ov;
  }

  // signal clock-keepers to exit
  if (tid == 0)
    __hip_atomic_fetch_add(done, 1, __ATOMIC_RELAXED, __HIP_MEMORY_SCOPE_AGENT);
}

// ---------------- diagnostic ----------------
__global__ void k_report(float* __restrict__ out, int n, float val)
{
  int tid = blockIdx.x * blockDim.x + threadIdx.x;
  int stride = gridDim.x * blockDim.x;
  for (int i = tid; i < n; i += stride) out[i] = val;
}

extern "C" void kernel_launch(void* const* d_in, const int* in_sizes, int n_in,
                              void* d_out, int out_size, void* d_ws, size_t ws_size,
                              hipStream_t stream)
{
  const float* x   = (const float*)d_in[0];
  const float* Wf  = (const float*)d_in[1];
  const float* bf_ = (const float*)d_in[2];
  const float* Wb  = (const float*)d_in[3];
  const float* bb_ = (const float*)d_in[4];
  const int*   len = (const int*)d_in[5];
  float* out = (float*)d_out;
  char* ws = (char*)d_ws;

  if (ws_size < WS_NEED) {
    k_report<<<2048, 256, 0, stream>>>(out, out_size,
                                       200.0f + (float)(ws_size >> 20) * 0.1f);
    return;
  }

  uint16_t* WX  = (uint16_t*)(ws + WX_OFF);
  uint16_t* WHp = (uint16_t*)(ws + WH_OFF);
  uint16_t* X   = (uint16_t*)(ws + X_OFF);
  uint16_t* H   = (uint16_t*)(ws + H_OFF);
  uint32_t* RST = (uint32_t*)(ws + RST_OFF);
  int*      TAG = (int*)(ws + TAG_OFF);
  int*      ZR  = (int*)(ws + ZR_OFF);
  int*      DN  = (int*)(ws + DONE_OFF);
  uint16_t* Z   = (uint16_t*)(ws + Z_OFF);

  k_init<<<64, 256, 0, stream>>>(len, RST, TAG, ZR, DN, H);
  k_wcast<<<4096, 256, 0, stream>>>(Wf, Wb, WX, WHp);
  k_xcast<<<16384, 256, 0, stream>>>(x, X);
  k_rec<<<256, 512, 0, stream>>>(WHp, WX, X, Z, bf_, bb_, RST, H, TAG, ZR, DN, out);
}